// Round 11
// baseline (253.548 us; speedup 1.0000x reference)
//
#include <hip/hip_runtime.h>
#include <math.h>

#define NN 50000
#define NE 800000

#define CH1 3125            // e1 chunk (4 floats/node -> 50 KB LDS planes)
#define C1  16
#define NB1D 8              // e1 dense slices (partials)
#define CH2 12500           // e2/e3 chunk
#define C2  4
#define NB2 32
#define SL2 (NE / NB2)      // 25000 (e3 scan)
#define QCAP 128
#define CAP 60000           // per dst-bin capacity (mean 50000, sigma~217)
#define BCAP 512            // k_bin per-chunk LDS buffer
#define BSL 2048            // k_bin edges per block

typedef unsigned short u16;

__device__ __forceinline__ float lrelu(float x, float s) { return x >= 0.f ? x : s * x; }

// Fused prologue. Blocks [0,64): image matmul. [64,456): per-node pack. [456,...): u16 cvt.
__global__ void k_pre(const float* __restrict__ x, const float* __restrict__ Wl,
                      const float* __restrict__ nodef,
                      const float* __restrict__ W1, const float* __restrict__ al1,
                      const float* __restrict__ ar1,
                      const int* __restrict__ src, const int* __restrict__ dst,
                      float* __restrict__ emb_acc, float* __restrict__ feat4,
                      float* __restrict__ er1, u16* __restrict__ src16,
                      u16* __restrict__ dst16) {
    int bid = blockIdx.x, t = threadIdx.x;
    if (bid < 64) {
        __shared__ float part[8][64];
        int kk = t & 31, rq = t >> 5;
        int r0 = bid * 64;
        float a0 = 0.f, a1 = 0.f;
        if (kk < 30) {
            for (int i = 0; i < 8; ++i) {
                int r = r0 + rq * 8 + i;
                float wv = Wl[r * 30 + kk];
                a0 += x[r] * wv;
                a1 += x[4096 + r] * wv;
            }
        }
        part[rq][kk] = a0;
        part[rq][32 + kk] = a1;
        __syncthreads();
        if (t < 60) {
            int g = t / 30, k = t - g * 30;
            float s = 0.f;
            #pragma unroll
            for (int rr = 0; rr < 8; ++rr) s += part[rr][g * 32 + k];
            atomicAdd(&emb_acc[g * 30 + k], s);
        }
    } else if (bid < 456) {
        __shared__ float sP[6];
        if (t < 6) {
            int c = t >> 1;
            const float* av = (t & 1) ? ar1 : al1;
            float s = 0.f;
            for (int f = 0; f < 80; ++f) s += W1[c * 160 + f] * av[f];
            sP[(t & 1) * 3 + c] = s;
        }
        __syncthreads();
        int b2 = bid - 64;
        int g = b2 / 196;
        int n = (b2 - g * 196) * 256 + t;
        if (n < NN) {
            const float* f = nodef + ((size_t)g * NN + n) * 3;
            float f0 = f[0], f1 = f[1], f2 = f[2];
            *(float4*)(feat4 + ((size_t)g * NN + n) * 4) =
                make_float4(f0, f1, f2, f0 * sP[0] + f1 * sP[1] + f2 * sP[2]);
            er1[g * NN + n] = f0 * sP[3] + f1 * sP[4] + f2 * sP[5];
        }
    } else {
        long flat = ((long)(bid - 456) * 256 + t) * 8;
        if (flat < 2L * 2 * NE) {
            int arr = flat >= 2L * NE;
            long rem = flat - (long)arr * 2 * NE;
            int g = rem >= NE;
            int e = (int)(rem - (long)g * NE);
            const int* ip = (arr ? dst : src) + (size_t)g * NE + e;
            int4 v0 = *(const int4*)ip;
            int4 v1 = *(const int4*)(ip + 4);
            uint4 o;
            o.x = (v0.x & 0xFFFF) | (v0.y << 16);
            o.y = (v0.z & 0xFFFF) | (v0.w << 16);
            o.z = (v1.x & 0xFFFF) | (v1.y << 16);
            o.w = (v1.z & 0xFFFF) | (v1.w << 16);
            *(uint4*)((arr ? dst16 : src16) + (size_t)g * NE + e) = o;
        }
    }
}

// Bin edges by dst-chunk: dbin[(g*16+c)*CAP + i] = (rel<<20)|e. LDS-staged, coalesced flush.
__global__ __launch_bounds__(256) void k_bin(const u16* __restrict__ dst16,
                                             unsigned* __restrict__ gctr,
                                             unsigned* __restrict__ dbin) {
    __shared__ unsigned buf[16][BCAP];
    __shared__ unsigned lctr[16];
    __shared__ unsigned sbase;
    int t = threadIdx.x, g = blockIdx.y;
    if (t < 16) lctr[t] = 0;
    __syncthreads();
    const u16* dp = dst16 + (size_t)g * NE;
    int e0 = blockIdx.x * BSL + t * 8;
    if (e0 < NE) {
        uint4 dv = *(const uint4*)(dp + e0);
        #pragma unroll
        for (int j = 0; j < 8; ++j) {
            unsigned word = (&dv.x)[j >> 1];
            unsigned d = (j & 1) ? (word >> 16) : (word & 0xFFFF);
            unsigned c = d / 3125;
            unsigned rel = d - c * 3125;
            unsigned pk = (rel << 20) | (unsigned)(e0 + j);
            unsigned slot = atomicAdd(&lctr[c], 1u);
            if (slot < BCAP) buf[c][slot] = pk;
            else {  // guaranteed-correct overflow fallback
                unsigned gp = atomicAdd(&gctr[g * 16 + c], 1u);
                if (gp < CAP) dbin[(size_t)(g * 16 + c) * CAP + gp] = pk;
            }
        }
    }
    __syncthreads();
    for (int c = 0; c < 16; ++c) {
        unsigned n = lctr[c] < BCAP ? lctr[c] : BCAP;
        if (n == 0) continue;
        if (t == 0) sbase = atomicAdd(&gctr[g * 16 + c], n);
        __syncthreads();
        unsigned* seg = dbin + (size_t)(g * 16 + c) * CAP + sbase;
        for (unsigned i = t; i < n; i += 256) seg[i] = buf[c][i];
        __syncthreads();
    }
}

// Dense e1: consume bin (all lanes hit). Plane-layout LDS accumulate, transpose flush.
__global__ __launch_bounds__(1024) void k_e1d(const unsigned* __restrict__ dbin,
                                              const unsigned* __restrict__ gctr,
                                              const u16* __restrict__ src16,
                                              const float* __restrict__ feat4,
                                              const float* __restrict__ er1,
                                              float* __restrict__ P) {
    __shared__ float sacc[4 * CH1];   // planes: [comp][rel] -> bank = rel%32 (random, ~free)
    __shared__ float sEr[CH1];
    int bx = blockIdx.x, c = blockIdx.y, g = blockIdx.z;
    for (int i = threadIdx.x; i < 4 * CH1; i += 1024) sacc[i] = 0.f;
    int base = c * CH1;
    for (int i = threadIdx.x; i < CH1; i += 1024) sEr[i] = er1[(size_t)g * NN + base + i];
    __syncthreads();
    const u16* sp = src16 + (size_t)g * NE;
    const float* f4 = feat4 + (size_t)g * NN * 4;
    const unsigned* seg = dbin + (size_t)(g * 16 + c) * CAP;
    unsigned size = gctr[g * 16 + c];
    for (unsigned i = bx * 1024 + threadIdx.x; i < size; i += NB1D * 1024) {
        unsigned p = seg[i];
        unsigned e = p & 0xFFFFFu;
        unsigned rel = p >> 20;
        unsigned s = sp[e];
        float4 F = *(const float4*)(f4 + (size_t)s * 4);
        float wv = __expf(lrelu(F.w + sEr[rel], 0.2f));
        atomicAdd(&sacc[rel], wv * F.x);
        atomicAdd(&sacc[CH1 + rel], wv * F.y);
        atomicAdd(&sacc[2 * CH1 + rel], wv * F.z);
        atomicAdd(&sacc[3 * CH1 + rel], wv);
    }
    __syncthreads();
    float* Pb = P + ((size_t)(g * C1 + c) * NB1D + bx) * (CH1 * 4);
    for (int i = threadIdx.x; i < CH1 * 4; i += 1024)
        Pb[i] = sacc[(i & 3) * CH1 + (i >> 2)];  // -> float4-per-node layout
}

// Dense e2 (den2): reuse dst bins, 4 bins per CH2 chunk.
__global__ __launch_bounds__(1024) void k_e2d(const unsigned* __restrict__ dbin,
                                              const unsigned* __restrict__ gctr,
                                              const u16* __restrict__ src16,
                                              const float* __restrict__ el2,
                                              const float* __restrict__ er2iv,
                                              float* __restrict__ P) {
    __shared__ float sden[CH2];
    int bx = blockIdx.x, c2 = blockIdx.y, g = blockIdx.z;
    for (int i = threadIdx.x; i < CH2; i += 1024) sden[i] = 0.f;
    __syncthreads();
    const u16* sp = src16 + (size_t)g * NE;
    const float* el = el2 + (size_t)g * NN;
    const float* er = er2iv + (size_t)g * NN * 2 + (size_t)c2 * CH2 * 2;
    for (int sub = 0; sub < 4; ++sub) {
        int c = c2 * 4 + sub;
        const unsigned* seg = dbin + (size_t)(g * 16 + c) * CAP;
        unsigned size = gctr[g * 16 + c];
        int roff = sub * CH1;
        for (unsigned i = bx * 1024 + threadIdx.x; i < size; i += NB2 * 1024) {
            unsigned p = seg[i];
            unsigned e = p & 0xFFFFFu;
            unsigned drel = roff + (p >> 20);
            float wv = __expf(lrelu(el[sp[e]] + er[2 * drel], 0.2f));
            atomicAdd(&sden[drel], wv);
        }
    }
    __syncthreads();
    float* Pb = P + ((size_t)(g * C2 + c2) * NB2 + bx) * CH2;
    for (int i = threadIdx.x; i < CH2; i += 1024) Pb[i] = sden[i];
}

// q: ushort8 scan + compaction (src-chunked): sq[rel] += exp(...) * invden2[d]
__global__ __launch_bounds__(1024) void k_e3c(const u16* __restrict__ src16,
                                              const u16* __restrict__ dst16,
                                              const float* __restrict__ el2,
                                              const float* __restrict__ er2iv,
                                              float* __restrict__ P) {
    __shared__ float sq[CH2];
    __shared__ unsigned squeue[16][QCAP];
    int b = blockIdx.x, c = blockIdx.y, g = blockIdx.z;
    for (int i = threadIdx.x; i < CH2; i += 1024) sq[i] = 0.f;
    __syncthreads();
    unsigned base = c * CH2;
    const u16* sp = src16 + (size_t)g * NE;
    const u16* dp = dst16 + (size_t)g * NE;
    const float* el = el2 + (size_t)g * NN + base;
    const float* er = er2iv + (size_t)g * NN * 2;
    int wid = threadIdx.x >> 6, lane = threadIdx.x & 63;
    unsigned* q = squeue[wid];
    unsigned long long lmask = (1ull << lane) - 1;
    int qn = 0;
    int e0 = b * SL2, eend = e0 + SL2;
    for (int it = 0; it < (SL2 + 8191) / 8192; ++it) {
        int ebase = e0 + it * 8192 + threadIdx.x * 8;
        uint4 sv = make_uint4(0xFFFFFFFFu, 0xFFFFFFFFu, 0xFFFFFFFFu, 0xFFFFFFFFu);
        if (ebase < eend) sv = *(const uint4*)(sp + ebase);
        #pragma unroll
        for (int j = 0; j < 8; ++j) {
            unsigned word = (&sv.x)[j >> 1];
            unsigned sj = (j & 1) ? (word >> 16) : (word & 0xFFFF);
            bool hit = (sj - base) < CH2;
            unsigned long long m = __ballot(hit);
            if (hit) q[qn + __popcll(m & lmask)] = (unsigned)(ebase + j);
            qn += __popcll(m);
            if (qn >= 64) {
                int ee = (int)q[lane];
                int rel = sp[ee] - base;
                float2 EI = *(const float2*)(er + 2 * dp[ee]);
                float wv = __expf(lrelu(el[rel] + EI.x, 0.2f));
                atomicAdd(&sq[rel], wv * EI.y);
                qn -= 64;
                if (lane < qn) q[lane] = q[64 + lane];
            }
        }
    }
    if (lane < qn) {
        int ee = (int)q[lane];
        int rel = sp[ee] - base;
        float2 EI = *(const float2*)(er + 2 * dp[ee]);
        float wv = __expf(lrelu(el[rel] + EI.x, 0.2f));
        atomicAdd(&sq[rel], wv * EI.y);
    }
    __syncthreads();
    float* Pb = P + ((size_t)(g * C2 + c) * NB2 + b) * CH2;
    for (int i = threadIdx.x; i < CH2; i += 1024) Pb[i] = sq[i];
}

// Generic partial reduce: out[idx*ostride+ooff] = (1/)sum_b P[...]
__global__ void k_red(const float* __restrict__ P, float* __restrict__ out,
                      int C, int NB, int CHW, int inv, int ostride, int ooff) {
    int T = 2 * C * CHW;
    int idx = blockIdx.x * blockDim.x + threadIdx.x;
    if (idx >= T) return;
    int gc = idx / CHW;
    int j = idx - gc * CHW;
    const float* Pp = P + ((size_t)gc * NB) * CHW + j;
    float s = 0.f;
    for (int b = 0; b < NB; ++b) s += Pp[(size_t)b * CHW];
    out[(size_t)idx * ostride + ooff] = inv ? (s != 0.f ? 1.f / s : 0.f) : s;
}

// Fused reduce(e1 partials, NB1D) + node stage: facc4, el2, er2.
__global__ void k_n1r(const float* __restrict__ P, const float* __restrict__ W1,
                      const float* __restrict__ b1, const float* __restrict__ W2,
                      const float* __restrict__ al2, const float* __restrict__ ar2,
                      float* __restrict__ facc4, float* __restrict__ el2,
                      float* __restrict__ er2iv) {
    __shared__ float sW[240], sB[80], sU[80], sV[80];
    for (int t = threadIdx.x; t < 80; t += blockDim.x) {
        sW[t] = W1[t];
        sW[80 + t] = W1[160 + t];
        sW[160 + t] = W1[320 + t];
        sB[t] = b1[t];
        float u = 0.f, v = 0.f;
        for (int j = 0; j < 30; ++j) {
            float wv = W2[t * 60 + j];
            u += wv * al2[j];
            v += wv * ar2[j];
        }
        sU[t] = u;
        sV[t] = v;
    }
    __syncthreads();
    int g = blockIdx.y;
    int n = blockIdx.x * blockDim.x + threadIdx.x;
    if (n >= NN) return;
    int c = n / CH1, rel = n - c * CH1;
    const float* Pp = P + ((size_t)(g * C1 + c) * NB1D) * (CH1 * 4) + rel * 4;
    float4 fa = make_float4(0.f, 0.f, 0.f, 0.f);
    for (int b = 0; b < NB1D; ++b) {
        float4 p = *(const float4*)(Pp + (size_t)b * (CH1 * 4));
        fa.x += p.x; fa.y += p.y; fa.z += p.z; fa.w += p.w;
    }
    *(float4*)(facc4 + ((size_t)g * NN + n) * 4) = fa;
    float inv = fa.w != 0.f ? 1.f / fa.w : 0.f;
    float c0 = fa.x * inv, c1 = fa.y * inv, c2 = fa.z * inv;
    float el = 0.f, er = 0.f;
    #pragma unroll
    for (int f = 0; f < 80; ++f) {
        float gg = c0 * sW[f] + c1 * sW[80 + f] + c2 * sW[160 + f] + sB[f];
        gg = gg > 0.f ? gg : 0.f;
        el += gg * sU[f];
        er += gg * sV[f];
    }
    el2[g * NN + n] = el;
    er2iv[((size_t)g * NN + n) * 2] = er;
}

// A[g][0..79] = sum_n q[n] * g1[n]
#define RT 128
__global__ void k_r(const float* __restrict__ facc4, const float* __restrict__ W1,
                    const float* __restrict__ b1, const float* __restrict__ q,
                    float* __restrict__ A) {
    __shared__ float4 sF[RT];
    __shared__ float sQ[RT];
    __shared__ float sW[240], sB[80];
    __shared__ float sA[240];
    int t = threadIdx.x;
    for (int i = t; i < 80; i += 256) {
        sW[i] = W1[i];
        sW[80 + i] = W1[160 + i];
        sW[160 + i] = W1[320 + i];
        sB[i] = b1[i];
    }
    int g = blockIdx.y;
    int grp = t / 80, f = t - grp * 80;
    float acc = 0.f;
    for (int n0 = blockIdx.x * RT; n0 < NN; n0 += gridDim.x * RT) {
        __syncthreads();
        if (t < RT) {
            int n = n0 + t;
            sF[t] = (n < NN) ? *(const float4*)(facc4 + ((size_t)g * NN + n) * 4)
                             : make_float4(0.f, 0.f, 0.f, 0.f);
        } else if (t < 2 * RT) {
            int n = n0 + t - RT;
            sQ[t - RT] = (n < NN) ? q[g * NN + n] : 0.f;
        }
        __syncthreads();
        if (grp < 3) {
            for (int i = grp; i < RT; i += 3) {
                float qn = sQ[i];
                if (qn == 0.f) continue;
                float4 fa = sF[i];
                float inv = fa.w != 0.f ? 1.f / fa.w : 0.f;
                float c0 = fa.x * inv, c1 = fa.y * inv, c2 = fa.z * inv;
                float gg = c0 * sW[f] + c1 * sW[80 + f] + c2 * sW[160 + f] + sB[f];
                gg = gg > 0.f ? gg : 0.f;
                acc += qn * gg;
            }
        }
    }
    if (grp < 3) sA[t] = acc;
    __syncthreads();
    if (t < 80) atomicAdd(&A[g * 80 + t], sA[t] + sA[80 + t] + sA[160 + t]);
}

// Final head (+ image conv tail). 256 threads.
__global__ void k_final(const float* __restrict__ A, const float* __restrict__ W2g,
                        const float* __restrict__ b2, const float* __restrict__ Wg1,
                        const float* __restrict__ bg1, const float* __restrict__ emb_acc,
                        const float* __restrict__ Wc1, const float* __restrict__ Wc2,
                        const float* __restrict__ vocab, const float* __restrict__ W2f,
                        const float* __restrict__ W3, float* __restrict__ out, int out_size) {
    __shared__ float emb[60];
    __shared__ float hh[80 * 30];
    __shared__ float a[60];
    __shared__ float hc[70];
    __shared__ float tt[80];
    __shared__ float lp[2];
    int t = threadIdx.x;
    if (t < 60) {
        emb[t] = emb_acc[t];
        int i = t / 30, j = t % 30;
        float acc = 0.f;
        for (int f = 0; f < 80; ++f) acc += A[i * 80 + f] * W2g[f * 60 + j];
        a[t] = acc * (1.f / NN) + b2[j];
    }
    __syncthreads();
    for (int p = t; p < 2400; p += 256) {
        int i = p / 30, j = p % 30;
        float v = Wc1[i * 2 + 0] * emb[j] + Wc1[i * 2 + 1] * emb[30 + j];
        hh[p] = lrelu(v, 0.01f);
    }
    __syncthreads();
    if (t < 30) {
        float acc = 0.f;
        for (int i = 0; i < 80; ++i) acc += Wc2[i] * hh[i * 30 + t];
        hc[30 + t] = lrelu(acc, 0.01f);
        float acg = bg1[t];
        for (int j = 0; j < 60; ++j) acg += a[j] * Wg1[j * 30 + t];
        hc[t] = acg;
        if (t < 10) hc[60 + t] = vocab[t];
    }
    __syncthreads();
    if (t < 80) {
        float acc = 0.f;
        for (int qd = 0; qd < 70; ++qd) acc += hc[qd] * W2f[qd * 80 + t];
        tt[t] = acc;
    }
    __syncthreads();
    if (t < 2) {
        float acc = 0.f;
        for (int p = 0; p < 80; ++p) acc += tt[p] * W3[p * 2 + t];
        lp[t] = acc;
    }
    __syncthreads();
    if (t == 0) {
        float m = fmaxf(lp[0], lp[1]);
        float lse = m + logf(expf(lp[0] - m) + expf(lp[1] - m));
        out[0] = lp[0] - lse;
        out[1] = lp[1] - lse;
    }
    for (int i = 2 + t; i < out_size; i += blockDim.x) out[i] = 0.f;
}

extern "C" void kernel_launch(void* const* d_in, const int* in_sizes, int n_in,
                              void* d_out, int out_size, void* d_ws, size_t ws_size,
                              hipStream_t stream) {
    const float* x        = (const float*)d_in[0];
    const float* vocab    = (const float*)d_in[1];
    const float* nodef    = (const float*)d_in[2];
    const int*   src      = (const int*)d_in[3];
    const int*   dst      = (const int*)d_in[4];
    const float* W_lin1   = (const float*)d_in[5];
    const float* Wc1      = (const float*)d_in[6];
    const float* Wc2      = (const float*)d_in[7];
    const float* gat1_W   = (const float*)d_in[8];
    const float* gat1_al  = (const float*)d_in[9];
    const float* gat1_ar  = (const float*)d_in[10];
    const float* gat1_b   = (const float*)d_in[11];
    const float* gat2_W   = (const float*)d_in[12];
    const float* gat2_al  = (const float*)d_in[13];
    const float* gat2_ar  = (const float*)d_in[14];
    const float* gat2_b   = (const float*)d_in[15];
    const float* Wg1      = (const float*)d_in[16];
    const float* bg1      = (const float*)d_in[17];
    const float* W2       = (const float*)d_in[18];
    const float* W3       = (const float*)d_in[19];
    (void)in_sizes; (void)n_in; (void)ws_size;

    float* w = (float*)d_ws;
    size_t off = 0;
    auto alloc = [&](size_t n) { size_t o = off; off += (n + 63) & ~(size_t)63; return o; };
    size_t o_emb  = alloc(64);   // zeroed
    size_t o_A    = alloc(192);  // zeroed
    size_t o_ctr  = alloc(64);   // zeroed (32 u32 bin counters)
    size_t o_feat = alloc((size_t)2 * NN * 4);
    size_t o_er1  = alloc(2 * NN);
    size_t o_el2  = alloc(2 * NN);
    size_t o_eriv = alloc((size_t)2 * NN * 2);
    size_t o_facc = alloc((size_t)2 * NN * 4);
    size_t o_q    = alloc(2 * NN);
    size_t o_s16  = alloc((size_t)2 * NE / 2);
    size_t o_d16  = alloc((size_t)2 * NE / 2);
    size_t o_bin  = alloc((size_t)2 * 16 * CAP);   // 7.68 MB (u32 entries)
    size_t o_P    = alloc((size_t)2 * C2 * NB2 * CH2);  // 12.8 MB partials
    u16* src16 = (u16*)(w + o_s16);
    u16* dst16 = (u16*)(w + o_d16);
    unsigned* gctr = (unsigned*)(w + o_ctr);
    unsigned* dbin = (unsigned*)(w + o_bin);

    hipMemsetAsync(w + o_emb, 0, (o_feat - o_emb) * sizeof(float), stream);
    int cvt_blocks = (2 * 2 * NE / 8 + 255) / 256;
    k_pre<<<456 + cvt_blocks, 256, 0, stream>>>(x, W_lin1, nodef, gat1_W, gat1_al, gat1_ar,
                                                src, dst, w + o_emb, w + o_feat, w + o_er1,
                                                src16, dst16);

    k_bin<<<dim3((NE + BSL - 1) / BSL, 2), 256, 0, stream>>>(dst16, gctr, dbin);

    k_e1d<<<dim3(NB1D, C1, 2), 1024, 0, stream>>>(dbin, gctr, src16, w + o_feat,
                                                  w + o_er1, w + o_P);
    k_n1r<<<dim3((NN + 255) / 256, 2), 256, 0, stream>>>(w + o_P, gat1_W, gat1_b, gat2_W,
                                                         gat2_al, gat2_ar, w + o_facc,
                                                         w + o_el2, w + o_eriv);

    k_e2d<<<dim3(NB2, C2, 2), 1024, 0, stream>>>(dbin, gctr, src16, w + o_el2,
                                                 w + o_eriv, w + o_P);
    k_red<<<(2 * NN + 1023) / 1024, 1024, 0, stream>>>(w + o_P, w + o_eriv,
                                                       C2, NB2, CH2, 1, 2, 1);

    k_e3c<<<dim3(NB2, C2, 2), 1024, 0, stream>>>(src16, dst16, w + o_el2, w + o_eriv, w + o_P);
    k_red<<<(2 * NN + 1023) / 1024, 1024, 0, stream>>>(w + o_P, w + o_q,
                                                       C2, NB2, CH2, 0, 1, 0);

    k_r<<<dim3(128, 2), 256, 0, stream>>>(w + o_facc, gat1_W, gat1_b, w + o_q, w + o_A);
    k_final<<<1, 256, 0, stream>>>(w + o_A, gat2_W, gat2_b, Wg1, bg1, w + o_emb,
                                   Wc1, Wc2, vocab, W2, W3, (float*)d_out, out_size);
}

// Round 13
// 175.102 us; speedup vs baseline: 1.4480x; 1.4480x over previous
//
#include <hip/hip_runtime.h>
#include <math.h>

#define NN 50000
#define NE 800000

#define CH1 3125            // bin chunk: 16 chunks of 3125 nodes
#define C1  16
#define NB1D 8              // e1/e3 dense slices (partials)
#define CH2 12500           // e2 accumulation chunk (4 dst-bins each)
#define C2  4
#define NB2 32
#define CAP 60000           // per-bin capacity (mean 50000, sigma ~217)
#define BSL 2048            // k_bin2 edges per block

typedef unsigned short u16;

__device__ __forceinline__ float lrelu(float x, float s) { return x >= 0.f ? x : s * x; }

// Fused prologue. Blocks [0,64): image matmul. [64,456): per-node pack. [456,...): u16 cvt.
__global__ void k_pre(const float* __restrict__ x, const float* __restrict__ Wl,
                      const float* __restrict__ nodef,
                      const float* __restrict__ W1, const float* __restrict__ al1,
                      const float* __restrict__ ar1,
                      const int* __restrict__ src, const int* __restrict__ dst,
                      float* __restrict__ emb_acc, float* __restrict__ feat4,
                      float* __restrict__ er1, u16* __restrict__ src16,
                      u16* __restrict__ dst16) {
    int bid = blockIdx.x, t = threadIdx.x;
    if (bid < 64) {
        __shared__ float part[8][64];
        int kk = t & 31, rq = t >> 5;
        int r0 = bid * 64;
        float a0 = 0.f, a1 = 0.f;
        if (kk < 30) {
            for (int i = 0; i < 8; ++i) {
                int r = r0 + rq * 8 + i;
                float wv = Wl[r * 30 + kk];
                a0 += x[r] * wv;
                a1 += x[4096 + r] * wv;
            }
        }
        part[rq][kk] = a0;
        part[rq][32 + kk] = a1;
        __syncthreads();
        if (t < 60) {
            int g = t / 30, k = t - g * 30;
            float s = 0.f;
            #pragma unroll
            for (int rr = 0; rr < 8; ++rr) s += part[rr][g * 32 + k];
            atomicAdd(&emb_acc[g * 30 + k], s);
        }
    } else if (bid < 456) {
        __shared__ float sP[6];
        if (t < 6) {
            int c = t >> 1;
            const float* av = (t & 1) ? ar1 : al1;
            float s = 0.f;
            for (int f = 0; f < 80; ++f) s += W1[c * 160 + f] * av[f];
            sP[(t & 1) * 3 + c] = s;
        }
        __syncthreads();
        int b2 = bid - 64;
        int g = b2 / 196;
        int n = (b2 - g * 196) * 256 + t;
        if (n < NN) {
            const float* f = nodef + ((size_t)g * NN + n) * 3;
            float f0 = f[0], f1 = f[1], f2 = f[2];
            *(float4*)(feat4 + ((size_t)g * NN + n) * 4) =
                make_float4(f0, f1, f2, f0 * sP[0] + f1 * sP[1] + f2 * sP[2]);
            er1[g * NN + n] = f0 * sP[3] + f1 * sP[4] + f2 * sP[5];
        }
    } else {
        long flat = ((long)(bid - 456) * 256 + t) * 8;
        if (flat < 2L * 2 * NE) {
            int arr = flat >= 2L * NE;
            long rem = flat - (long)arr * 2 * NE;
            int g = rem >= NE;
            int e = (int)(rem - (long)g * NE);
            const int* ip = (arr ? dst : src) + (size_t)g * NE + e;
            int4 v0 = *(const int4*)ip;
            int4 v1 = *(const int4*)(ip + 4);
            uint4 o;
            o.x = (v0.x & 0xFFFF) | (v0.y << 16);
            o.y = (v0.z & 0xFFFF) | (v0.w << 16);
            o.z = (v1.x & 0xFFFF) | (v1.y << 16);
            o.w = (v1.z & 0xFFFF) | (v1.w << 16);
            *(uint4*)((arr ? dst16 : src16) + (size_t)g * NE + e) = o;
        }
    }
}

// Two-pass per-block counting-sort binning. y: 0=dst,1=src. z: graph.
// Entry layout INSIDE each array is (g*16+c); counters use (a*2+g)*16+c.
__global__ __launch_bounds__(256) void k_bin2(const u16* __restrict__ dst16,
                                              const u16* __restrict__ src16,
                                              unsigned* __restrict__ gctr,
                                              unsigned* __restrict__ dbin,
                                              unsigned* __restrict__ sbin) {
    __shared__ unsigned wcnt[4][16];
    __shared__ unsigned wbase[4][16];
    __shared__ unsigned wrun[4][16];
    __shared__ unsigned sbase[16];
    int t = threadIdx.x, a = blockIdx.y, g = blockIdx.z;
    int wid = t >> 6;
    if (t < 64) wcnt[t >> 4][t & 15] = 0;
    __syncthreads();
    const u16* ip = (a ? src16 : dst16) + (size_t)g * NE;
    unsigned* bin = (a ? sbin : dbin);
    int cbase = (a * 2 + g) * 16;   // counter base (global, disambiguates a)
    int bbase = g * 16;             // bin base (local within dbin/sbin)
    int e0 = blockIdx.x * BSL + t * 8;
    uint4 v = make_uint4(0, 0, 0, 0);
    unsigned cj[8], relj[8];
    bool act = e0 < NE;
    if (act) {
        v = *(const uint4*)(ip + e0);
        #pragma unroll
        for (int j = 0; j < 8; ++j) {
            unsigned word = (&v.x)[j >> 1];
            unsigned d = (j & 1) ? (word >> 16) : (word & 0xFFFF);
            unsigned c = d / CH1;
            cj[j] = c;
            relj[j] = d - c * CH1;
            atomicAdd(&wcnt[wid][c], 1u);
        }
    }
    __syncthreads();
    if (t < 16) {
        unsigned s = wcnt[0][t] + wcnt[1][t] + wcnt[2][t] + wcnt[3][t];
        sbase[t] = atomicAdd(&gctr[cbase + t], s);
    }
    __syncthreads();
    if (t < 64) {
        int w = t >> 4, b = t & 15;
        unsigned off = 0;
        for (int w2 = 0; w2 < w; ++w2) off += wcnt[w2][b];
        wbase[w][b] = sbase[b] + off;
        wrun[w][b] = 0;
    }
    __syncthreads();
    if (act) {
        #pragma unroll
        for (int j = 0; j < 8; ++j) {
            unsigned c = cj[j];
            unsigned slot = atomicAdd(&wrun[wid][c], 1u);
            unsigned pos = wbase[wid][c] + slot;
            if (pos < CAP)
                bin[(size_t)(bbase + c) * CAP + pos] = (relj[j] << 20) | (unsigned)(e0 + j);
        }
    }
}

// Dense e1: consume dst bin. Plane-layout LDS accumulate, transpose flush.
__global__ __launch_bounds__(1024) void k_e1d(const unsigned* __restrict__ dbin,
                                              const unsigned* __restrict__ gctr,
                                              const u16* __restrict__ src16,
                                              const float* __restrict__ feat4,
                                              const float* __restrict__ er1,
                                              float* __restrict__ P) {
    __shared__ float sacc[4 * CH1];
    __shared__ float sEr[CH1];
    int bx = blockIdx.x, c = blockIdx.y, g = blockIdx.z;
    for (int i = threadIdx.x; i < 4 * CH1; i += 1024) sacc[i] = 0.f;
    int base = c * CH1;
    for (int i = threadIdx.x; i < CH1; i += 1024) sEr[i] = er1[(size_t)g * NN + base + i];
    __syncthreads();
    const u16* sp = src16 + (size_t)g * NE;
    const float* f4 = feat4 + (size_t)g * NN * 4;
    const unsigned* seg = dbin + (size_t)(g * 16 + c) * CAP;
    unsigned size = gctr[g * 16 + c];
    for (unsigned i = bx * 1024 + threadIdx.x; i < size; i += NB1D * 1024) {
        unsigned p = seg[i];
        unsigned e = p & 0xFFFFFu;
        unsigned rel = p >> 20;
        unsigned s = sp[e];
        float4 F = *(const float4*)(f4 + (size_t)s * 4);
        float wv = __expf(lrelu(F.w + sEr[rel], 0.2f));
        atomicAdd(&sacc[rel], wv * F.x);
        atomicAdd(&sacc[CH1 + rel], wv * F.y);
        atomicAdd(&sacc[2 * CH1 + rel], wv * F.z);
        atomicAdd(&sacc[3 * CH1 + rel], wv);
    }
    __syncthreads();
    float* Pb = P + ((size_t)(g * C1 + c) * NB1D + bx) * (CH1 * 4);
    for (int i = threadIdx.x; i < CH1 * 4; i += 1024)
        Pb[i] = sacc[(i & 3) * CH1 + (i >> 2)];
}

// Dense e2 (den2): 4 dst bins per CH2 chunk.
__global__ __launch_bounds__(1024) void k_e2d(const unsigned* __restrict__ dbin,
                                              const unsigned* __restrict__ gctr,
                                              const u16* __restrict__ src16,
                                              const float* __restrict__ el2,
                                              const float* __restrict__ er2iv,
                                              float* __restrict__ P) {
    __shared__ float sden[CH2];
    int bx = blockIdx.x, c2 = blockIdx.y, g = blockIdx.z;
    for (int i = threadIdx.x; i < CH2; i += 1024) sden[i] = 0.f;
    __syncthreads();
    const u16* sp = src16 + (size_t)g * NE;
    const float* el = el2 + (size_t)g * NN;
    for (int sub = 0; sub < 4; ++sub) {
        int c = c2 * 4 + sub;
        const unsigned* seg = dbin + (size_t)(g * 16 + c) * CAP;
        unsigned size = gctr[g * 16 + c];
        int roff = sub * CH1;
        const float* er = er2iv + ((size_t)g * NN + (size_t)c * CH1) * 2;
        for (unsigned i = bx * 1024 + threadIdx.x; i < size; i += NB2 * 1024) {
            unsigned p = seg[i];
            unsigned e = p & 0xFFFFFu;
            unsigned rel = p >> 20;
            float wv = __expf(lrelu(el[sp[e]] + er[2 * rel], 0.2f));
            atomicAdd(&sden[roff + rel], wv);
        }
    }
    __syncthreads();
    float* Pb = P + ((size_t)(g * C2 + c2) * NB2 + bx) * CH2;
    for (int i = threadIdx.x; i < CH2; i += 1024) Pb[i] = sden[i];
}

// Dense e3 (q): consume src bin. sq[rel] += exp(lrelu(el2[s]+er2[d])) * invden2[d].
__global__ __launch_bounds__(1024) void k_e3d(const unsigned* __restrict__ sbin,
                                              const unsigned* __restrict__ gctr,
                                              const u16* __restrict__ dst16,
                                              const float* __restrict__ el2,
                                              const float* __restrict__ er2iv,
                                              float* __restrict__ P) {
    __shared__ float sq[CH1];
    __shared__ float sEl[CH1];
    int bx = blockIdx.x, c = blockIdx.y, g = blockIdx.z;
    for (int i = threadIdx.x; i < CH1; i += 1024) {
        sq[i] = 0.f;
        sEl[i] = el2[(size_t)g * NN + c * CH1 + i];
    }
    __syncthreads();
    const u16* dp = dst16 + (size_t)g * NE;
    const float* er = er2iv + (size_t)g * NN * 2;
    const unsigned* seg = sbin + (size_t)(g * 16 + c) * CAP;   // local layout
    unsigned size = gctr[(2 + g) * 16 + c];                    // src counters
    for (unsigned i = bx * 1024 + threadIdx.x; i < size; i += NB1D * 1024) {
        unsigned p = seg[i];
        unsigned e = p & 0xFFFFFu;
        unsigned rel = p >> 20;
        unsigned d = dp[e];
        float2 EI = *(const float2*)(er + 2 * (size_t)d);
        float wv = __expf(lrelu(sEl[rel] + EI.x, 0.2f));
        atomicAdd(&sq[rel], wv * EI.y);
    }
    __syncthreads();
    float* Pb = P + ((size_t)(g * C1 + c) * NB1D + bx) * CH1;
    for (int i = threadIdx.x; i < CH1; i += 1024) Pb[i] = sq[i];
}

// Generic partial reduce: out[idx*ostride+ooff] = (1/)sum_b P[...]
__global__ void k_red(const float* __restrict__ P, float* __restrict__ out,
                      int C, int NB, int CHW, int inv, int ostride, int ooff) {
    int T = 2 * C * CHW;
    int idx = blockIdx.x * blockDim.x + threadIdx.x;
    if (idx >= T) return;
    int gc = idx / CHW;
    int j = idx - gc * CHW;
    const float* Pp = P + ((size_t)gc * NB) * CHW + j;
    float s = 0.f;
    for (int b = 0; b < NB; ++b) s += Pp[(size_t)b * CHW];
    out[(size_t)idx * ostride + ooff] = inv ? (s != 0.f ? 1.f / s : 0.f) : s;
}

// Fused reduce(e1 partials, NB1D) + node stage: facc4, el2, er2.
__global__ void k_n1r(const float* __restrict__ P, const float* __restrict__ W1,
                      const float* __restrict__ b1, const float* __restrict__ W2,
                      const float* __restrict__ al2, const float* __restrict__ ar2,
                      float* __restrict__ facc4, float* __restrict__ el2,
                      float* __restrict__ er2iv) {
    __shared__ float sW[240], sB[80], sU[80], sV[80];
    for (int t = threadIdx.x; t < 80; t += blockDim.x) {
        sW[t] = W1[t];
        sW[80 + t] = W1[160 + t];
        sW[160 + t] = W1[320 + t];
        sB[t] = b1[t];
        float u = 0.f, v = 0.f;
        for (int j = 0; j < 30; ++j) {
            float wv = W2[t * 60 + j];
            u += wv * al2[j];
            v += wv * ar2[j];
        }
        sU[t] = u;
        sV[t] = v;
    }
    __syncthreads();
    int g = blockIdx.y;
    int n = blockIdx.x * blockDim.x + threadIdx.x;
    if (n >= NN) return;
    int c = n / CH1, rel = n - c * CH1;
    const float* Pp = P + ((size_t)(g * C1 + c) * NB1D) * (CH1 * 4) + rel * 4;
    float4 fa = make_float4(0.f, 0.f, 0.f, 0.f);
    for (int b = 0; b < NB1D; ++b) {
        float4 p = *(const float4*)(Pp + (size_t)b * (CH1 * 4));
        fa.x += p.x; fa.y += p.y; fa.z += p.z; fa.w += p.w;
    }
    *(float4*)(facc4 + ((size_t)g * NN + n) * 4) = fa;
    float inv = fa.w != 0.f ? 1.f / fa.w : 0.f;
    float c0 = fa.x * inv, c1 = fa.y * inv, c2 = fa.z * inv;
    float el = 0.f, er = 0.f;
    #pragma unroll
    for (int f = 0; f < 80; ++f) {
        float gg = c0 * sW[f] + c1 * sW[80 + f] + c2 * sW[160 + f] + sB[f];
        gg = gg > 0.f ? gg : 0.f;
        el += gg * sU[f];
        er += gg * sV[f];
    }
    el2[g * NN + n] = el;
    er2iv[((size_t)g * NN + n) * 2] = er;
}

// A[g][0..79] = sum_n q[n] * g1[n]
#define RT 128
__global__ void k_r(const float* __restrict__ facc4, const float* __restrict__ W1,
                    const float* __restrict__ b1, const float* __restrict__ q,
                    float* __restrict__ A) {
    __shared__ float4 sF[RT];
    __shared__ float sQ[RT];
    __shared__ float sW[240], sB[80];
    __shared__ float sA[240];
    int t = threadIdx.x;
    for (int i = t; i < 80; i += 256) {
        sW[i] = W1[i];
        sW[80 + i] = W1[160 + i];
        sW[160 + i] = W1[320 + i];
        sB[i] = b1[i];
    }
    int g = blockIdx.y;
    int grp = t / 80, f = t - grp * 80;
    float acc = 0.f;
    for (int n0 = blockIdx.x * RT; n0 < NN; n0 += gridDim.x * RT) {
        __syncthreads();
        if (t < RT) {
            int n = n0 + t;
            sF[t] = (n < NN) ? *(const float4*)(facc4 + ((size_t)g * NN + n) * 4)
                             : make_float4(0.f, 0.f, 0.f, 0.f);
        } else if (t < 2 * RT) {
            int n = n0 + t - RT;
            sQ[t - RT] = (n < NN) ? q[g * NN + n] : 0.f;
        }
        __syncthreads();
        if (grp < 3) {
            for (int i = grp; i < RT; i += 3) {
                float qn = sQ[i];
                if (qn == 0.f) continue;
                float4 fa = sF[i];
                float inv = fa.w != 0.f ? 1.f / fa.w : 0.f;
                float c0 = fa.x * inv, c1 = fa.y * inv, c2 = fa.z * inv;
                float gg = c0 * sW[f] + c1 * sW[80 + f] + c2 * sW[160 + f] + sB[f];
                gg = gg > 0.f ? gg : 0.f;
                acc += qn * gg;
            }
        }
    }
    if (grp < 3) sA[t] = acc;
    __syncthreads();
    if (t < 80) atomicAdd(&A[g * 80 + t], sA[t] + sA[80 + t] + sA[160 + t]);
}

// Final head (+ image conv tail). 256 threads.
__global__ void k_final(const float* __restrict__ A, const float* __restrict__ W2g,
                        const float* __restrict__ b2, const float* __restrict__ Wg1,
                        const float* __restrict__ bg1, const float* __restrict__ emb_acc,
                        const float* __restrict__ Wc1, const float* __restrict__ Wc2,
                        const float* __restrict__ vocab, const float* __restrict__ W2f,
                        const float* __restrict__ W3, float* __restrict__ out, int out_size) {
    __shared__ float emb[60];
    __shared__ float hh[80 * 30];
    __shared__ float a[60];
    __shared__ float hc[70];
    __shared__ float tt[80];
    __shared__ float lp[2];
    int t = threadIdx.x;
    if (t < 60) {
        emb[t] = emb_acc[t];
        int i = t / 30, j = t % 30;
        float acc = 0.f;
        for (int f = 0; f < 80; ++f) acc += A[i * 80 + f] * W2g[f * 60 + j];
        a[t] = acc * (1.f / NN) + b2[j];
    }
    __syncthreads();
    for (int p = t; p < 2400; p += 256) {
        int i = p / 30, j = p % 30;
        float v = Wc1[i * 2 + 0] * emb[j] + Wc1[i * 2 + 1] * emb[30 + j];
        hh[p] = lrelu(v, 0.01f);
    }
    __syncthreads();
    if (t < 30) {
        float acc = 0.f;
        for (int i = 0; i < 80; ++i) acc += Wc2[i] * hh[i * 30 + t];
        hc[30 + t] = lrelu(acc, 0.01f);
        float acg = bg1[t];
        for (int j = 0; j < 60; ++j) acg += a[j] * Wg1[j * 30 + t];
        hc[t] = acg;
        if (t < 10) hc[60 + t] = vocab[t];
    }
    __syncthreads();
    if (t < 80) {
        float acc = 0.f;
        for (int qd = 0; qd < 70; ++qd) acc += hc[qd] * W2f[qd * 80 + t];
        tt[t] = acc;
    }
    __syncthreads();
    if (t < 2) {
        float acc = 0.f;
        for (int p = 0; p < 80; ++p) acc += tt[p] * W3[p * 2 + t];
        lp[t] = acc;
    }
    __syncthreads();
    if (t == 0) {
        float m = fmaxf(lp[0], lp[1]);
        float lse = m + logf(expf(lp[0] - m) + expf(lp[1] - m));
        out[0] = lp[0] - lse;
        out[1] = lp[1] - lse;
    }
    for (int i = 2 + t; i < out_size; i += blockDim.x) out[i] = 0.f;
}

extern "C" void kernel_launch(void* const* d_in, const int* in_sizes, int n_in,
                              void* d_out, int out_size, void* d_ws, size_t ws_size,
                              hipStream_t stream) {
    const float* x        = (const float*)d_in[0];
    const float* vocab    = (const float*)d_in[1];
    const float* nodef    = (const float*)d_in[2];
    const int*   src      = (const int*)d_in[3];
    const int*   dst      = (const int*)d_in[4];
    const float* W_lin1   = (const float*)d_in[5];
    const float* Wc1      = (const float*)d_in[6];
    const float* Wc2      = (const float*)d_in[7];
    const float* gat1_W   = (const float*)d_in[8];
    const float* gat1_al  = (const float*)d_in[9];
    const float* gat1_ar  = (const float*)d_in[10];
    const float* gat1_b   = (const float*)d_in[11];
    const float* gat2_W   = (const float*)d_in[12];
    const float* gat2_al  = (const float*)d_in[13];
    const float* gat2_ar  = (const float*)d_in[14];
    const float* gat2_b   = (const float*)d_in[15];
    const float* Wg1      = (const float*)d_in[16];
    const float* bg1      = (const float*)d_in[17];
    const float* W2       = (const float*)d_in[18];
    const float* W3       = (const float*)d_in[19];
    (void)in_sizes; (void)n_in; (void)ws_size;

    float* w = (float*)d_ws;
    size_t off = 0;
    auto alloc = [&](size_t n) { size_t o = off; off += (n + 63) & ~(size_t)63; return o; };
    size_t o_emb  = alloc(64);   // zeroed
    size_t o_A    = alloc(192);  // zeroed
    size_t o_ctr  = alloc(64);   // zeroed (64 u32 bin counters)
    size_t o_feat = alloc((size_t)2 * NN * 4);
    size_t o_er1  = alloc(2 * NN);
    size_t o_el2  = alloc(2 * NN);
    size_t o_eriv = alloc((size_t)2 * NN * 2);
    size_t o_facc = alloc((size_t)2 * NN * 4);
    size_t o_q    = alloc(2 * NN);
    size_t o_s16  = alloc((size_t)2 * NE / 2);
    size_t o_d16  = alloc((size_t)2 * NE / 2);
    size_t o_dbin = alloc((size_t)2 * 16 * CAP);
    size_t o_sbin = alloc((size_t)2 * 16 * CAP);
    size_t o_P    = alloc((size_t)2 * C2 * NB2 * CH2);  // 3.2M floats (>= all partial uses)
    u16* src16 = (u16*)(w + o_s16);
    u16* dst16 = (u16*)(w + o_d16);
    unsigned* gctr = (unsigned*)(w + o_ctr);
    unsigned* dbin = (unsigned*)(w + o_dbin);
    unsigned* sbin = (unsigned*)(w + o_sbin);

    hipMemsetAsync(w + o_emb, 0, (o_feat - o_emb) * sizeof(float), stream);
    int cvt_blocks = (2 * 2 * NE / 8 + 255) / 256;
    k_pre<<<456 + cvt_blocks, 256, 0, stream>>>(x, W_lin1, nodef, gat1_W, gat1_al, gat1_ar,
                                                src, dst, w + o_emb, w + o_feat, w + o_er1,
                                                src16, dst16);

    k_bin2<<<dim3((NE + BSL - 1) / BSL, 2, 2), 256, 0, stream>>>(dst16, src16, gctr,
                                                                 dbin, sbin);

    k_e1d<<<dim3(NB1D, C1, 2), 1024, 0, stream>>>(dbin, gctr, src16, w + o_feat,
                                                  w + o_er1, w + o_P);
    k_n1r<<<dim3((NN + 255) / 256, 2), 256, 0, stream>>>(w + o_P, gat1_W, gat1_b, gat2_W,
                                                         gat2_al, gat2_ar, w + o_facc,
                                                         w + o_el2, w + o_eriv);

    k_e2d<<<dim3(NB2, C2, 2), 1024, 0, stream>>>(dbin, gctr, src16, w + o_el2,
                                                 w + o_eriv, w + o_P);
    k_red<<<(2 * NN + 1023) / 1024, 1024, 0, stream>>>(w + o_P, w + o_eriv,
                                                       C2, NB2, CH2, 1, 2, 1);

    k_e3d<<<dim3(NB1D, C1, 2), 1024, 0, stream>>>(sbin, gctr, dst16, w + o_el2,
                                                  w + o_eriv, w + o_P);
    k_red<<<(2 * NN + 1023) / 1024, 1024, 0, stream>>>(w + o_P, w + o_q,
                                                       C1, NB1D, CH1, 0, 1, 0);

    k_r<<<dim3(128, 2), 256, 0, stream>>>(w + o_facc, gat1_W, gat1_b, w + o_q, w + o_A);
    k_final<<<1, 256, 0, stream>>>(w + o_A, gat2_W, gat2_b, Wg1, bg1, w + o_emb,
                                   Wc1, Wc2, vocab, W2, W3, (float*)d_out, out_size);
}